// Round 5
// baseline (298.703 us; speedup 1.0000x reference)
//
#include <hip/hip_runtime.h>
#include <math.h>

#define BB 4
#define LQ 8400
#define NH 8
#define LVTOT 8500
#define HD 32

typedef __attribute__((ext_vector_type(8))) short short8;
typedef __attribute__((ext_vector_type(4))) float f32x4;
typedef unsigned short ushort_t;

__device__ __forceinline__ ushort_t f2bf(float f) {
    union { float f; unsigned u; } v; v.f = f;
    unsigned r = v.u + 0x7fffu + ((v.u >> 16) & 1u);   // RNE
    return (ushort_t)(r >> 16);
}
__device__ __forceinline__ float bflo(unsigned u) {
    union { unsigned u; float f; } x; x.u = u << 16; return x.f;
}
__device__ __forceinline__ float bfhi(unsigned u) {
    union { unsigned u; float f; } x; x.u = u & 0xffff0000u; return x.f;
}

// ---------------------------------------------------------------------------
// fp32 -> bf16 cast, float4/ushort4 vectorized
// ---------------------------------------------------------------------------
__global__ __launch_bounds__(256) void cast_bf16(
    const float* __restrict__ src, ushort_t* __restrict__ dst, int n4)
{
    int i = blockIdx.x * 256 + threadIdx.x;
    if (i < n4) {
        float4 f = ((const float4*)src)[i];
        ushort4 o;
        o.x = f2bf(f.x); o.y = f2bf(f.y); o.z = f2bf(f.z); o.w = f2bf(f.w);
        ((ushort4*)dst)[i] = o;
    }
}

// ---------------------------------------------------------------------------
// Build BT (transposed bf16 weights), 896 rows x 256 k:
// rows 0..255 = Wv^T, 256..639 = [Woff|Wattn]^T, 640..895 = Wo^T
// ---------------------------------------------------------------------------
__global__ __launch_bounds__(256) void prep_weights(
    const float* __restrict__ Wv, const float* __restrict__ Woff,
    const float* __restrict__ Wattn, const float* __restrict__ Wo,
    ushort_t* __restrict__ BT)
{
    int idx = blockIdx.x * 256 + threadIdx.x;   // 896*256
    int r = idx >> 8, k = idx & 255;
    float v;
    if (r < 256) v = Wv[k * 256 + r];
    else if (r < 640) {
        int n = r - 256;
        v = (n < 256) ? Woff[k * 256 + n] : Wattn[k * 128 + (n - 256)];
    } else v = Wo[k * 256 + (r - 640)];
    BT[idx] = f2bf(v);
}

// ---------------------------------------------------------------------------
// bf16 MFMA GEMM: C[M x N] = A[M x 256](bf16) @ BT^T + bias, 128x128 tile,
// 4 waves (2x2 of 64x64), BK=64, XOR-swizzled LDS:
//   physical_kseg = logical_kseg ^ (row & 7)
// MODE 0: Ch -> vperm bf16 [b][h][pix][d]
// MODE 1: cols<256 -> Ch = off bf16 [M][256]; cols>=256 -> C1h = awl bf16 [M][128]
// MODE 2: Cf -> plain fp32 [M][256]
// ---------------------------------------------------------------------------
template<int MODE>
__global__ __launch_bounds__(256, 2) void gemm_mfma(
    const ushort_t* __restrict__ A, int M,
    const ushort_t* __restrict__ BT,
    const float* __restrict__ bias0, const float* __restrict__ bias1,
    float* __restrict__ Cf, ushort_t* __restrict__ Ch, ushort_t* __restrict__ C1h)
{
    __shared__ ushort_t Asl[128 * 64];
    __shared__ ushort_t Bsl[128 * 64];

    const int tid  = threadIdx.x;
    const int m0   = blockIdx.x * 128;
    const int n0   = blockIdx.y * 128;
    const int wave = tid >> 6, lane = tid & 63;
    const int wm   = (wave >> 1) * 64, wn = (wave & 1) * 64;
    const int quad = lane >> 4, mr = lane & 15;
    const int srow = tid >> 3;        // 0..31
    const int scol = tid & 7;         // logical k segment

    f32x4 acc[4][4];
    #pragma unroll
    for (int i = 0; i < 4; i++)
        #pragma unroll
        for (int j = 0; j < 4; j++) acc[i][j] = (f32x4){0.f, 0.f, 0.f, 0.f};

    for (int k0 = 0; k0 < 256; k0 += 64) {
        short8 ra[4], rb[4];
        #pragma unroll
        for (int i = 0; i < 4; i++) {
            int m = i * 32 + srow;
            int am = min(m0 + m, M - 1);
            ra[i] = *(const short8*)(A  + (size_t)am * 256 + k0 + scol * 8);
            int bn = n0 + m;
            rb[i] = *(const short8*)(BT + (size_t)bn * 256 + k0 + scol * 8);
        }
        __syncthreads();
        #pragma unroll
        for (int i = 0; i < 4; i++) {
            int m = i * 32 + srow;
            int pseg = scol ^ (m & 7);     // physical = logical ^ (row&7)
            *(short8*)&Asl[m * 64 + pseg * 8] = ra[i];
            *(short8*)&Bsl[m * 64 + pseg * 8] = rb[i];
        }
        __syncthreads();
        #pragma unroll
        for (int ks = 0; ks < 2; ks++) {
            short8 af[4], bf[4];
            const int ksl = ks * 4 + quad;
            #pragma unroll
            for (int i = 0; i < 4; i++) {
                int m = wm + i * 16 + mr;
                af[i] = *(const short8*)&Asl[m * 64 + (ksl ^ (m & 7)) * 8];
                int n = wn + i * 16 + mr;
                bf[i] = *(const short8*)&Bsl[n * 64 + (ksl ^ (n & 7)) * 8];
            }
            #pragma unroll
            for (int i = 0; i < 4; i++)
                #pragma unroll
                for (int j = 0; j < 4; j++)
                    acc[i][j] = __builtin_amdgcn_mfma_f32_16x16x32_bf16(
                        af[i], bf[j], acc[i][j], 0, 0, 0);
        }
        __syncthreads();
    }

    #pragma unroll
    for (int i = 0; i < 4; i++) {
        const int rbase = m0 + wm + i * 16 + quad * 4;
        #pragma unroll
        for (int j = 0; j < 4; j++) {
            const int c = n0 + wn + j * 16 + mr;
            #pragma unroll
            for (int reg = 0; reg < 4; reg++) {
                int row = rbase + reg;
                if (row >= M) continue;
                float val = acc[i][j][reg];
                if (MODE == 0) {
                    float o = val + bias0[c];
                    int b = row / LVTOT, pix = row - b * LVTOT;
                    int h = c >> 5, d = c & 31;
                    Ch[(((size_t)(b * NH + h)) * LVTOT + pix) * HD + d] = f2bf(o);
                } else if (MODE == 1) {
                    if (c < 256) Ch[(size_t)row * 256 + c] = f2bf(val + bias0[c]);
                    else         C1h[(size_t)row * 128 + (c - 256)] = f2bf(val + bias1[c - 256]);
                } else {
                    Cf[(size_t)row * 256 + c] = val + bias0[c];
                }
            }
        }
    }
}

// ---------------------------------------------------------------------------
// Sampler v3: block = 8 queries.
// Phase A: thread = one (q,h,l,p) slot; softmax via __shfl_xor over the
//          16-lane (q,h) group; weights + byte-offsets -> LDS (stride 17).
// Phase B: 4 lanes/head x 8 bf16 dims (uint4 = 16B gathers); wave = 2 queries.
// ---------------------------------------------------------------------------
__global__ __launch_bounds__(256) void msda_sample(
    const ushort_t* __restrict__ vperm, const ushort_t* __restrict__ off,
    const ushort_t* __restrict__ awl, const float* __restrict__ refp,
    ushort_t* __restrict__ sampled)
{
    __shared__ float  s_ref[64];
    __shared__ float4 s_wv[1088];   // (q*8+h)*17 + (l*4+p), q<8
    __shared__ int4   s_iv[1088];

    const int tid = threadIdx.x;
    const int bq0 = blockIdx.x * 8;

    if (tid < 64) s_ref[tid] = refp[(size_t)bq0 * 8 + tid];
    __syncthreads();

    const int Hs[4]   = {80, 40, 20, 10};
    const int base[4] = {0, 6400, 8000, 8400};

    #pragma unroll
    for (int it = 0; it < 4; it++) {
        const int s = it * 256 + tid;
        const int q = s >> 7, r = s & 127;
        const int h = r >> 4, l = (r >> 2) & 3, p = r & 3;
        const int bq = bq0 + q;
        const int Wl = Hs[l], Hl = Hs[l];
        unsigned od = *(const unsigned*)(off + (size_t)bq * 256 + h * 32 + l * 8 + p * 2);
        float ox = bflo(od), oy = bfhi(od);
        float lgt = bflo((unsigned)awl[(size_t)bq * 128 + h * 16 + l * 4 + p]);
        // softmax across the 16-lane (q,h) group
        float mx = lgt;
        mx = fmaxf(mx, __shfl_xor(mx, 1, 16));
        mx = fmaxf(mx, __shfl_xor(mx, 2, 16));
        mx = fmaxf(mx, __shfl_xor(mx, 4, 16));
        mx = fmaxf(mx, __shfl_xor(mx, 8, 16));
        float e = __expf(lgt - mx);
        float sum = e;
        sum += __shfl_xor(sum, 1, 16);
        sum += __shfl_xor(sum, 2, 16);
        sum += __shfl_xor(sum, 4, 16);
        sum += __shfl_xor(sum, 8, 16);
        float aw = e / sum;

        float rx = s_ref[q * 8 + l * 2 + 0];
        float ry = s_ref[q * 8 + l * 2 + 1];
        float x = rx * (float)Wl + ox - 0.5f;
        float y = ry * (float)Hl + oy - 0.5f;
        float x0f = floorf(x), y0f = floorf(y);
        float wx = x - x0f, wy = y - y0f;
        int x0 = (int)x0f, y0 = (int)y0f;
        bool vx0 = (x0 >= 0) & (x0 < Wl);
        bool vx1 = (x0 + 1 >= 0) & (x0 + 1 < Wl);
        bool vy0 = (y0 >= 0) & (y0 < Hl);
        bool vy1 = (y0 + 1 >= 0) & (y0 + 1 < Hl);
        int cx0 = min(max(x0, 0), Wl - 1);
        int cx1 = min(max(x0 + 1, 0), Wl - 1);
        int cy0 = min(max(y0, 0), Hl - 1);
        int cy1 = min(max(y0 + 1, 0), Hl - 1);
        float w00 = (vx0 && vy0) ? (1.f - wx) * (1.f - wy) * aw : 0.f;
        float w01 = (vx1 && vy0) ? wx * (1.f - wy) * aw : 0.f;
        float w10 = (vx0 && vy1) ? (1.f - wx) * wy * aw : 0.f;
        float w11 = (vx1 && vy1) ? wx * wy * aw : 0.f;
        const int rec = (q * 8 + h) * 17 + (l * 4 + p);
        s_wv[rec] = make_float4(w00, w01, w10, w11);
        s_iv[rec] = make_int4((base[l] + cy0 * Wl + cx0) << 6,
                              (base[l] + cy0 * Wl + cx1) << 6,
                              (base[l] + cy1 * Wl + cx0) << 6,
                              (base[l] + cy1 * Wl + cx1) << 6);
    }
    __syncthreads();

    const int q  = tid >> 5;            // 8 queries / block, wave = 2 queries
    const int h  = (tid >> 2) & 7;
    const int dl = (tid & 3) * 8;       // 8 dims per lane
    const int bq = bq0 + q;
    const int b  = bq / LQ;
    const char* vb = (const char*)vperm + (((size_t)(b * NH + h)) * LVTOT * HD + dl) * 2;

    float acc[8];
    #pragma unroll
    for (int d = 0; d < 8; d++) acc[d] = 0.f;

    #pragma unroll
    for (int pt = 0; pt < 16; pt++) {
        const int rec = (q * 8 + h) * 17 + pt;
        float4 w  = s_wv[rec];
        int4   iv = s_iv[rec];
        uint4 v0 = *(const uint4*)(vb + iv.x);
        uint4 v1 = *(const uint4*)(vb + iv.y);
        uint4 v2 = *(const uint4*)(vb + iv.z);
        uint4 v3 = *(const uint4*)(vb + iv.w);
        acc[0] += w.x * bflo(v0.x) + w.y * bflo(v1.x) + w.z * bflo(v2.x) + w.w * bflo(v3.x);
        acc[1] += w.x * bfhi(v0.x) + w.y * bfhi(v1.x) + w.z * bfhi(v2.x) + w.w * bfhi(v3.x);
        acc[2] += w.x * bflo(v0.y) + w.y * bflo(v1.y) + w.z * bflo(v2.y) + w.w * bflo(v3.y);
        acc[3] += w.x * bfhi(v0.y) + w.y * bfhi(v1.y) + w.z * bfhi(v2.y) + w.w * bfhi(v3.y);
        acc[4] += w.x * bflo(v0.z) + w.y * bflo(v1.z) + w.z * bflo(v2.z) + w.w * bflo(v3.z);
        acc[5] += w.x * bfhi(v0.z) + w.y * bfhi(v1.z) + w.z * bfhi(v2.z) + w.w * bfhi(v3.z);
        acc[6] += w.x * bflo(v0.w) + w.y * bflo(v1.w) + w.z * bflo(v2.w) + w.w * bflo(v3.w);
        acc[7] += w.x * bfhi(v0.w) + w.y * bfhi(v1.w) + w.z * bfhi(v2.w) + w.w * bfhi(v3.w);
    }
    short8 o;
    #pragma unroll
    for (int d = 0; d < 8; d++) o[d] = (short)f2bf(acc[d]);
    *(short8*)(sampled + (size_t)bq * 256 + h * 32 + dl) = o;
}

extern "C" void kernel_launch(void* const* d_in, const int* in_sizes, int n_in,
                              void* d_out, int out_size, void* d_ws, size_t ws_size,
                              hipStream_t stream) {
    const float* query = (const float*)d_in[0];
    const float* refp  = (const float*)d_in[1];
    const float* value = (const float*)d_in[2];
    const float* Wv    = (const float*)d_in[4];
    const float* bv    = (const float*)d_in[5];
    const float* Woff  = (const float*)d_in[6];
    const float* boff  = (const float*)d_in[7];
    const float* Wattn = (const float*)d_in[8];
    const float* battn = (const float*)d_in[9];
    const float* Wo    = (const float*)d_in[10];
    const float* bo    = (const float*)d_in[11];
    float* out = (float*)d_out;

    ushort_t* ws = (ushort_t*)d_ws;
    ushort_t* off_b   = ws;                       // 33600*256
    ushort_t* awl_b   = off_b + 8601600;          // 33600*128
    ushort_t* value_b = awl_b + 4300800;          // 34000*256
    ushort_t* query_b = value_b + 8704000;        // 33600*256 (aliased w/ sampled)
    ushort_t* vperm_b = query_b + 8601600;        // 34000*256
    ushort_t* BT      = vperm_b + 8704000;        // 896*256
    ushort_t* sampled_b = query_b;                // alias: query dead after GEMM2

    const int M1 = BB * LVTOT;  // 34000
    const int M2 = BB * LQ;     // 33600

    cast_bf16<<<dim3(8500), 256, 0, stream>>>(value, value_b, 8704000 / 4);
    cast_bf16<<<dim3(8400), 256, 0, stream>>>(query, query_b, 8601600 / 4);
    prep_weights<<<dim3(896), 256, 0, stream>>>(Wv, Woff, Wattn, Wo, BT);

    gemm_mfma<0><<<dim3(266, 2), 256, 0, stream>>>(
        value_b, M1, BT, bv, nullptr, nullptr, vperm_b, nullptr);
    gemm_mfma<1><<<dim3(263, 3), 256, 0, stream>>>(
        query_b, M2, BT + 65536, boff, battn, nullptr, off_b, awl_b);

    msda_sample<<<dim3(M2 / 8), 256, 0, stream>>>(vperm_b, off_b, awl_b, refp, sampled_b);

    gemm_mfma<2><<<dim3(263, 2), 256, 0, stream>>>(
        sampled_b, M2, BT + 65536 + 98304, bo, nullptr, out, nullptr, nullptr);
}

// Round 6
// 260.769 us; speedup vs baseline: 1.1455x; 1.1455x over previous
//
#include <hip/hip_runtime.h>
#include <math.h>

#define BB 4
#define LQ 8400
#define NH 8
#define LVTOT 8500
#define HD 32

typedef __attribute__((ext_vector_type(8))) short short8;
typedef __attribute__((ext_vector_type(4))) float f32x4;
typedef unsigned short ushort_t;

__device__ __forceinline__ ushort_t f2bf(float f) {
    union { float f; unsigned u; } v; v.f = f;
    unsigned r = v.u + 0x7fffu + ((v.u >> 16) & 1u);   // RNE
    return (ushort_t)(r >> 16);
}
__device__ __forceinline__ float bflo(unsigned u) {
    union { unsigned u; float f; } x; x.u = u << 16; return x.f;
}
__device__ __forceinline__ float bfhi(unsigned u) {
    union { unsigned u; float f; } x; x.u = u & 0xffff0000u; return x.f;
}

// ---------------------------------------------------------------------------
// fp32 -> bf16 cast, float4/ushort4 vectorized
// ---------------------------------------------------------------------------
__global__ __launch_bounds__(256) void cast_bf16(
    const float* __restrict__ src, ushort_t* __restrict__ dst, int n4)
{
    int i = blockIdx.x * 256 + threadIdx.x;
    if (i < n4) {
        float4 f = ((const float4*)src)[i];
        ushort4 o;
        o.x = f2bf(f.x); o.y = f2bf(f.y); o.z = f2bf(f.z); o.w = f2bf(f.w);
        ((ushort4*)dst)[i] = o;
    }
}

// ---------------------------------------------------------------------------
// Build BT (transposed bf16 weights), 896 rows x 256 k:
// rows 0..255 = Wv^T, 256..639 = [Woff|Wattn]^T, 640..895 = Wo^T
// ---------------------------------------------------------------------------
__global__ __launch_bounds__(256) void prep_weights(
    const float* __restrict__ Wv, const float* __restrict__ Woff,
    const float* __restrict__ Wattn, const float* __restrict__ Wo,
    ushort_t* __restrict__ BT)
{
    int idx = blockIdx.x * 256 + threadIdx.x;   // 896*256
    int r = idx >> 8, k = idx & 255;
    float v;
    if (r < 256) v = Wv[k * 256 + r];
    else if (r < 640) {
        int n = r - 256;
        v = (n < 256) ? Woff[k * 256 + n] : Wattn[k * 128 + (n - 256)];
    } else v = Wo[k * 256 + (r - 640)];
    BT[idx] = f2bf(v);
}

// ---------------------------------------------------------------------------
// bf16 MFMA GEMM: C[M x N] = A[M x 256](bf16) @ BT^T + bias, 128x128 tile,
// 4 waves (2x2 of 64x64), BK=64, XOR-swizzled LDS:
//   physical_kseg = logical_kseg ^ (row & 7)
// MODE 0: Ch -> vperm bf16 [b][h][pix][d]
// MODE 1: cols<256 -> Ch = off bf16 [M][256]; cols>=256 -> C1h = awl bf16 [M][128]
// MODE 2: Cf -> plain fp32 [M][256]
// ---------------------------------------------------------------------------
template<int MODE>
__global__ __launch_bounds__(256, 2) void gemm_mfma(
    const ushort_t* __restrict__ A, int M,
    const ushort_t* __restrict__ BT,
    const float* __restrict__ bias0, const float* __restrict__ bias1,
    float* __restrict__ Cf, ushort_t* __restrict__ Ch, ushort_t* __restrict__ C1h)
{
    __shared__ ushort_t Asl[128 * 64];
    __shared__ ushort_t Bsl[128 * 64];

    const int tid  = threadIdx.x;
    const int m0   = blockIdx.x * 128;
    const int n0   = blockIdx.y * 128;
    const int wave = tid >> 6, lane = tid & 63;
    const int wm   = (wave >> 1) * 64, wn = (wave & 1) * 64;
    const int quad = lane >> 4, mr = lane & 15;
    const int srow = tid >> 3;        // 0..31
    const int scol = tid & 7;         // logical k segment

    f32x4 acc[4][4];
    #pragma unroll
    for (int i = 0; i < 4; i++)
        #pragma unroll
        for (int j = 0; j < 4; j++) acc[i][j] = (f32x4){0.f, 0.f, 0.f, 0.f};

    for (int k0 = 0; k0 < 256; k0 += 64) {
        short8 ra[4], rb[4];
        #pragma unroll
        for (int i = 0; i < 4; i++) {
            int m = i * 32 + srow;
            int am = min(m0 + m, M - 1);
            ra[i] = *(const short8*)(A  + (size_t)am * 256 + k0 + scol * 8);
            int bn = n0 + m;
            rb[i] = *(const short8*)(BT + (size_t)bn * 256 + k0 + scol * 8);
        }
        __syncthreads();
        #pragma unroll
        for (int i = 0; i < 4; i++) {
            int m = i * 32 + srow;
            int pseg = scol ^ (m & 7);     // physical = logical ^ (row&7)
            *(short8*)&Asl[m * 64 + pseg * 8] = ra[i];
            *(short8*)&Bsl[m * 64 + pseg * 8] = rb[i];
        }
        __syncthreads();
        #pragma unroll
        for (int ks = 0; ks < 2; ks++) {
            short8 af[4], bf[4];
            const int ksl = ks * 4 + quad;
            #pragma unroll
            for (int i = 0; i < 4; i++) {
                int m = wm + i * 16 + mr;
                af[i] = *(const short8*)&Asl[m * 64 + (ksl ^ (m & 7)) * 8];
                int n = wn + i * 16 + mr;
                bf[i] = *(const short8*)&Bsl[n * 64 + (ksl ^ (n & 7)) * 8];
            }
            #pragma unroll
            for (int i = 0; i < 4; i++)
                #pragma unroll
                for (int j = 0; j < 4; j++)
                    acc[i][j] = __builtin_amdgcn_mfma_f32_16x16x32_bf16(
                        af[i], bf[j], acc[i][j], 0, 0, 0);
        }
        __syncthreads();
    }

    #pragma unroll
    for (int i = 0; i < 4; i++) {
        const int rbase = m0 + wm + i * 16 + quad * 4;
        #pragma unroll
        for (int j = 0; j < 4; j++) {
            const int c = n0 + wn + j * 16 + mr;
            #pragma unroll
            for (int reg = 0; reg < 4; reg++) {
                int row = rbase + reg;
                if (row >= M) continue;
                float val = acc[i][j][reg];
                if (MODE == 0) {
                    float o = val + bias0[c];
                    int b = row / LVTOT, pix = row - b * LVTOT;
                    int h = c >> 5, d = c & 31;
                    Ch[(((size_t)(b * NH + h)) * LVTOT + pix) * HD + d] = f2bf(o);
                } else if (MODE == 1) {
                    if (c < 256) Ch[(size_t)row * 256 + c] = f2bf(val + bias0[c]);
                    else         C1h[(size_t)row * 128 + (c - 256)] = f2bf(val + bias1[c - 256]);
                } else {
                    Cf[(size_t)row * 256 + c] = val + bias0[c];
                }
            }
        }
    }
}

// ---------------------------------------------------------------------------
// Sampler v4 (round-4 shape + bf16 sidebands): block = 4 queries.
// Phase A: 512 slots = (q,h,l,p); direct bf16 loads of off/awl; softmax via
//          __shfl_xor over the 16-lane (q,h) group; weights + byte offsets
//          -> LDS (stride-17 records).
// Phase B: 1 wave per query, 8 lanes per head, 4 bf16 dims/lane (uint2).
// ---------------------------------------------------------------------------
__global__ __launch_bounds__(256) void msda_sample(
    const ushort_t* __restrict__ vperm, const ushort_t* __restrict__ off,
    const ushort_t* __restrict__ awl, const float* __restrict__ refp,
    ushort_t* __restrict__ sampled)
{
    __shared__ float  s_ref[32];
    __shared__ float4 s_wv[544];   // (q*8+h)*17 + (l*4+p), q<4
    __shared__ int4   s_iv[544];

    const int tid = threadIdx.x;
    const int bq0 = blockIdx.x * 4;

    if (tid < 32) s_ref[tid] = refp[(size_t)bq0 * 8 + tid];
    __syncthreads();

    const int Hs[4]   = {80, 40, 20, 10};
    const int base[4] = {0, 6400, 8000, 8400};

    #pragma unroll
    for (int it = 0; it < 2; it++) {
        const int s = it * 256 + tid;
        const int q = s >> 7, r = s & 127;
        const int h = r >> 4, l = (r >> 2) & 3, p = r & 3;
        const int bq = bq0 + q;
        const int Wl = Hs[l], Hl = Hs[l];
        unsigned od = *(const unsigned*)(off + (size_t)bq * 256 + h * 32 + l * 8 + p * 2);
        float ox = bflo(od), oy = bfhi(od);
        float lgt = bflo((unsigned)awl[(size_t)bq * 128 + h * 16 + l * 4 + p]);
        // softmax across the 16-lane (q,h) group
        float mx = lgt;
        mx = fmaxf(mx, __shfl_xor(mx, 1, 16));
        mx = fmaxf(mx, __shfl_xor(mx, 2, 16));
        mx = fmaxf(mx, __shfl_xor(mx, 4, 16));
        mx = fmaxf(mx, __shfl_xor(mx, 8, 16));
        float e = __expf(lgt - mx);
        float sum = e;
        sum += __shfl_xor(sum, 1, 16);
        sum += __shfl_xor(sum, 2, 16);
        sum += __shfl_xor(sum, 4, 16);
        sum += __shfl_xor(sum, 8, 16);
        float aw = e / sum;

        float rx = s_ref[q * 8 + l * 2 + 0];
        float ry = s_ref[q * 8 + l * 2 + 1];
        float x = rx * (float)Wl + ox - 0.5f;
        float y = ry * (float)Hl + oy - 0.5f;
        float x0f = floorf(x), y0f = floorf(y);
        float wx = x - x0f, wy = y - y0f;
        int x0 = (int)x0f, y0 = (int)y0f;
        bool vx0 = (x0 >= 0) & (x0 < Wl);
        bool vx1 = (x0 + 1 >= 0) & (x0 + 1 < Wl);
        bool vy0 = (y0 >= 0) & (y0 < Hl);
        bool vy1 = (y0 + 1 >= 0) & (y0 + 1 < Hl);
        int cx0 = min(max(x0, 0), Wl - 1);
        int cx1 = min(max(x0 + 1, 0), Wl - 1);
        int cy0 = min(max(y0, 0), Hl - 1);
        int cy1 = min(max(y0 + 1, 0), Hl - 1);
        float w00 = (vx0 && vy0) ? (1.f - wx) * (1.f - wy) * aw : 0.f;
        float w01 = (vx1 && vy0) ? wx * (1.f - wy) * aw : 0.f;
        float w10 = (vx0 && vy1) ? (1.f - wx) * wy * aw : 0.f;
        float w11 = (vx1 && vy1) ? wx * wy * aw : 0.f;
        const int rec = (q * 8 + h) * 17 + (l * 4 + p);
        s_wv[rec] = make_float4(w00, w01, w10, w11);
        s_iv[rec] = make_int4((base[l] + cy0 * Wl + cx0) << 6,
                              (base[l] + cy0 * Wl + cx1) << 6,
                              (base[l] + cy1 * Wl + cx0) << 6,
                              (base[l] + cy1 * Wl + cx1) << 6);
    }
    __syncthreads();

    const int q    = tid >> 6;          // wave = query
    const int lane = tid & 63;
    const int h    = lane >> 3;
    const int d4   = (lane & 7) * 4;    // 4 dims per lane
    const int bq   = bq0 + q;
    const int b    = bq / LQ;
    const char* vb = (const char*)vperm + (((size_t)(b * NH + h)) * LVTOT * HD + d4) * 2;

    float4 acc = make_float4(0.f, 0.f, 0.f, 0.f);
    #pragma unroll
    for (int pt = 0; pt < 16; pt++) {
        const int rec = (q * 8 + h) * 17 + pt;
        float4 w  = s_wv[rec];
        int4   iv = s_iv[rec];
        uint2 v0 = *(const uint2*)(vb + iv.x);
        uint2 v1 = *(const uint2*)(vb + iv.y);
        uint2 v2 = *(const uint2*)(vb + iv.z);
        uint2 v3 = *(const uint2*)(vb + iv.w);
        acc.x += w.x * bflo(v0.x) + w.y * bflo(v1.x) + w.z * bflo(v2.x) + w.w * bflo(v3.x);
        acc.y += w.x * bfhi(v0.x) + w.y * bfhi(v1.x) + w.z * bfhi(v2.x) + w.w * bfhi(v3.x);
        acc.z += w.x * bflo(v0.y) + w.y * bflo(v1.y) + w.z * bflo(v2.y) + w.w * bflo(v3.y);
        acc.w += w.x * bfhi(v0.y) + w.y * bfhi(v1.y) + w.z * bfhi(v2.y) + w.w * bfhi(v3.y);
    }
    ushort4 o;
    o.x = f2bf(acc.x); o.y = f2bf(acc.y); o.z = f2bf(acc.z); o.w = f2bf(acc.w);
    *(ushort4*)(sampled + (size_t)bq * 256 + h * 32 + d4) = o;
}

extern "C" void kernel_launch(void* const* d_in, const int* in_sizes, int n_in,
                              void* d_out, int out_size, void* d_ws, size_t ws_size,
                              hipStream_t stream) {
    const float* query = (const float*)d_in[0];
    const float* refp  = (const float*)d_in[1];
    const float* value = (const float*)d_in[2];
    const float* Wv    = (const float*)d_in[4];
    const float* bv    = (const float*)d_in[5];
    const float* Woff  = (const float*)d_in[6];
    const float* boff  = (const float*)d_in[7];
    const float* Wattn = (const float*)d_in[8];
    const float* battn = (const float*)d_in[9];
    const float* Wo    = (const float*)d_in[10];
    const float* bo    = (const float*)d_in[11];
    float* out = (float*)d_out;

    ushort_t* ws = (ushort_t*)d_ws;
    ushort_t* off_b   = ws;                       // 33600*256
    ushort_t* awl_b   = off_b + 8601600;          // 33600*128
    ushort_t* value_b = awl_b + 4300800;          // 34000*256
    ushort_t* query_b = value_b + 8704000;        // 33600*256 (aliased w/ sampled)
    ushort_t* vperm_b = query_b + 8601600;        // 34000*256
    ushort_t* BT      = vperm_b + 8704000;        // 896*256
    ushort_t* sampled_b = query_b;                // alias: query dead after GEMM2

    const int M1 = BB * LVTOT;  // 34000
    const int M2 = BB * LQ;     // 33600

    cast_bf16<<<dim3(8500), 256, 0, stream>>>(value, value_b, 8704000 / 4);
    cast_bf16<<<dim3(8400), 256, 0, stream>>>(query, query_b, 8601600 / 4);
    prep_weights<<<dim3(896), 256, 0, stream>>>(Wv, Woff, Wattn, Wo, BT);

    gemm_mfma<0><<<dim3(266, 2), 256, 0, stream>>>(
        value_b, M1, BT, bv, nullptr, nullptr, vperm_b, nullptr);
    gemm_mfma<1><<<dim3(263, 3), 256, 0, stream>>>(
        query_b, M2, BT + 65536, boff, battn, nullptr, off_b, awl_b);

    msda_sample<<<dim3(M2 / 4), 256, 0, stream>>>(vperm_b, off_b, awl_b, refp, sampled_b);

    gemm_mfma<2><<<dim3(263, 2), 256, 0, stream>>>(
        sampled_b, M2, BT + 65536 + 98304, bo, nullptr, out, nullptr, nullptr);
}

// Round 7
// 257.051 us; speedup vs baseline: 1.1620x; 1.0145x over previous
//
#include <hip/hip_runtime.h>
#include <math.h>

#define BB 4
#define LQ 8400
#define NH 8
#define LVTOT 8500
#define HD 32

typedef __attribute__((ext_vector_type(8))) short short8;
typedef __attribute__((ext_vector_type(4))) float f32x4;
typedef unsigned short ushort_t;

__device__ __forceinline__ ushort_t f2bf(float f) {
    union { float f; unsigned u; } v; v.f = f;
    unsigned r = v.u + 0x7fffu + ((v.u >> 16) & 1u);   // RNE
    return (ushort_t)(r >> 16);
}
__device__ __forceinline__ float bflo(unsigned u) {
    union { unsigned u; float f; } x; x.u = u << 16; return x.f;
}
__device__ __forceinline__ float bfhi(unsigned u) {
    union { unsigned u; float f; } x; x.u = u & 0xffff0000u; return x.f;
}

// async global->LDS DMA, 16 B per lane (wave-uniform LDS base + lane*16)
__device__ __forceinline__ void dma16(const ushort_t* g, ushort_t* l) {
    __builtin_amdgcn_global_load_lds(
        (const __attribute__((address_space(1))) void*)g,
        (__attribute__((address_space(3))) void*)l, 16, 0, 0);
}

// ---------------------------------------------------------------------------
// fp32 -> bf16 cast
// ---------------------------------------------------------------------------
__global__ __launch_bounds__(256) void cast_bf16(
    const float* __restrict__ src, ushort_t* __restrict__ dst, int n4)
{
    int i = blockIdx.x * 256 + threadIdx.x;
    if (i < n4) {
        float4 f = ((const float4*)src)[i];
        ushort4 o;
        o.x = f2bf(f.x); o.y = f2bf(f.y); o.z = f2bf(f.z); o.w = f2bf(f.w);
        ((ushort4*)dst)[i] = o;
    }
}

// ---------------------------------------------------------------------------
// Build BT (transposed bf16 weights), 896 rows x 256 k
// ---------------------------------------------------------------------------
__global__ __launch_bounds__(256) void prep_weights(
    const float* __restrict__ Wv, const float* __restrict__ Woff,
    const float* __restrict__ Wattn, const float* __restrict__ Wo,
    ushort_t* __restrict__ BT)
{
    int idx = blockIdx.x * 256 + threadIdx.x;   // 896*256
    int r = idx >> 8, k = idx & 255;
    float v;
    if (r < 256) v = Wv[k * 256 + r];
    else if (r < 640) {
        int n = r - 256;
        v = (n < 256) ? Woff[k * 256 + n] : Wattn[k * 128 + (n - 256)];
    } else v = Wo[k * 256 + (r - 640)];
    BT[idx] = f2bf(v);
}

// ---------------------------------------------------------------------------
// Shared GEMM core: 128x128 tile, 4 waves (2x2 of 64x64), BK=64.
// Staging via global_load_lds dwordx4; XOR swizzle applied on the GLOBAL
// address (lane reads segment (lane&7)^(m&7)) so the DMA's linear
// base+lane*16 LDS placement yields physical seg = logical ^ (row&7).
// ---------------------------------------------------------------------------
__device__ __forceinline__ void gemm_core(
    const ushort_t* __restrict__ A, const ushort_t* __restrict__ B, int M,
    int m0, int n0, ushort_t* Asl, ushort_t* Bsl, f32x4 acc[4][4])
{
    const int tid  = threadIdx.x;
    const int wave = tid >> 6, lane = tid & 63;
    const int quad = lane >> 4, mr = lane & 15;
    const int wm   = (wave >> 1) * 64, wn = (wave & 1) * 64;
    const int oct  = lane >> 3;       // 0..7 row-in-wave-slab
    const int bseg = lane & 7;        // physical 16B slot within row

    for (int k0 = 0; k0 < 256; k0 += 64) {
        __syncthreads();              // prior iteration's reads done
        #pragma unroll
        for (int i = 0; i < 4; i++) {
            int m  = i * 32 + wave * 8 + oct;          // block-relative row
            int gs = bseg ^ (m & 7);                   // swizzled source seg
            int am = min(m0 + m, M - 1);
            dma16(A + (size_t)am * 256 + k0 + gs * 8,
                  Asl + (size_t)(i * 32 + wave * 8) * 64 + lane * 8);
            int bn = n0 + m;
            dma16(B + (size_t)bn * 256 + k0 + gs * 8,
                  Bsl + (size_t)(i * 32 + wave * 8) * 64 + lane * 8);
        }
        __syncthreads();              // DMA landed (vmcnt drained at barrier)
        #pragma unroll
        for (int ks = 0; ks < 2; ks++) {
            short8 af[4], bf[4];
            const int ksl = ks * 4 + quad;
            #pragma unroll
            for (int i = 0; i < 4; i++) {
                int m = wm + i * 16 + mr;
                af[i] = *(const short8*)&Asl[m * 64 + (ksl ^ (m & 7)) * 8];
                int n = wn + i * 16 + mr;
                bf[i] = *(const short8*)&Bsl[n * 64 + (ksl ^ (n & 7)) * 8];
            }
            #pragma unroll
            for (int i = 0; i < 4; i++)
                #pragma unroll
                for (int j = 0; j < 4; j++)
                    acc[i][j] = __builtin_amdgcn_mfma_f32_16x16x32_bf16(
                        af[i], bf[j], acc[i][j], 0, 0, 0);
        }
    }
}

// ---------------------------------------------------------------------------
// Fused GEMM1 (value->vperm, 532 blocks) + GEMM2 (query->off/awl, 789 blocks)
// ---------------------------------------------------------------------------
__global__ __launch_bounds__(256, 3) void gemm_fused(
    const ushort_t* __restrict__ Av, const ushort_t* __restrict__ Aq,
    const ushort_t* __restrict__ BT,
    const float* __restrict__ bv, const float* __restrict__ boff,
    const float* __restrict__ battn,
    ushort_t* __restrict__ vperm, ushort_t* __restrict__ off_b,
    ushort_t* __restrict__ awl_b)
{
    __shared__ ushort_t Asl[128 * 64];
    __shared__ ushort_t Bsl[128 * 64];

    const int bid = blockIdx.x;
    int mode, m0, n0, M;
    const ushort_t *A, *B;
    if (bid < 532) { mode = 0; m0 = (bid % 266) * 128; n0 = (bid / 266) * 128;
                     A = Av; B = BT; M = 34000; }
    else { int b2 = bid - 532;
           mode = 1; m0 = (b2 % 263) * 128; n0 = (b2 / 263) * 128;
           A = Aq; B = BT + 65536; M = 33600; }

    f32x4 acc[4][4];
    #pragma unroll
    for (int i = 0; i < 4; i++)
        #pragma unroll
        for (int j = 0; j < 4; j++) acc[i][j] = (f32x4){0.f, 0.f, 0.f, 0.f};

    gemm_core(A, B, M, m0, n0, Asl, Bsl, acc);

    const int tid  = threadIdx.x;
    const int wave = tid >> 6, lane = tid & 63;
    const int quad = lane >> 4, mr = lane & 15;
    const int wm   = (wave >> 1) * 64, wn = (wave & 1) * 64;

    #pragma unroll
    for (int i = 0; i < 4; i++) {
        const int rbase = m0 + wm + i * 16 + quad * 4;
        #pragma unroll
        for (int j = 0; j < 4; j++) {
            const int c = n0 + wn + j * 16 + mr;
            #pragma unroll
            for (int reg = 0; reg < 4; reg++) {
                int row = rbase + reg;
                if (row >= M) continue;
                float val = acc[i][j][reg];
                if (mode == 0) {
                    float o = val + bv[c];
                    int b = row / LVTOT, pix = row - b * LVTOT;
                    int h = c >> 5, d = c & 31;
                    vperm[(((size_t)(b * NH + h)) * LVTOT + pix) * HD + d] = f2bf(o);
                } else {
                    if (c < 256) off_b[(size_t)row * 256 + c] = f2bf(val + boff[c]);
                    else awl_b[(size_t)row * 128 + (c - 256)] = f2bf(val + battn[c - 256]);
                }
            }
        }
    }
}

// ---------------------------------------------------------------------------
// GEMM3: sampled(bf16) @ Wo + bo -> out fp32
// ---------------------------------------------------------------------------
__global__ __launch_bounds__(256, 3) void gemm_out(
    const ushort_t* __restrict__ A, const ushort_t* __restrict__ BT,
    const float* __restrict__ bo, float* __restrict__ out)
{
    __shared__ ushort_t Asl[128 * 64];
    __shared__ ushort_t Bsl[128 * 64];

    const int m0 = (blockIdx.x % 263) * 128;
    const int n0 = (blockIdx.x / 263) * 128;
    const int M = 33600;

    f32x4 acc[4][4];
    #pragma unroll
    for (int i = 0; i < 4; i++)
        #pragma unroll
        for (int j = 0; j < 4; j++) acc[i][j] = (f32x4){0.f, 0.f, 0.f, 0.f};

    gemm_core(A, BT, M, m0, n0, Asl, Bsl, acc);

    const int tid  = threadIdx.x;
    const int wave = tid >> 6, lane = tid & 63;
    const int quad = lane >> 4, mr = lane & 15;
    const int wm   = (wave >> 1) * 64, wn = (wave & 1) * 64;

    #pragma unroll
    for (int i = 0; i < 4; i++) {
        const int rbase = m0 + wm + i * 16 + quad * 4;
        #pragma unroll
        for (int j = 0; j < 4; j++) {
            const int c = n0 + wn + j * 16 + mr;
            #pragma unroll
            for (int reg = 0; reg < 4; reg++) {
                int row = rbase + reg;
                if (row >= M) continue;
                out[(size_t)row * 256 + c] = acc[i][j][reg] + bo[c];
            }
        }
    }
}

// ---------------------------------------------------------------------------
// Sampler v4 (unchanged from round 6): block = 4 queries.
// ---------------------------------------------------------------------------
__global__ __launch_bounds__(256) void msda_sample(
    const ushort_t* __restrict__ vperm, const ushort_t* __restrict__ off,
    const ushort_t* __restrict__ awl, const float* __restrict__ refp,
    ushort_t* __restrict__ sampled)
{
    __shared__ float  s_ref[32];
    __shared__ float4 s_wv[544];   // (q*8+h)*17 + (l*4+p), q<4
    __shared__ int4   s_iv[544];

    const int tid = threadIdx.x;
    const int bq0 = blockIdx.x * 4;

    if (tid < 32) s_ref[tid] = refp[(size_t)bq0 * 8 + tid];
    __syncthreads();

    const int Hs[4]   = {80, 40, 20, 10};
    const int base[4] = {0, 6400, 8000, 8400};

    #pragma unroll
    for (int it = 0; it < 2; it++) {
        const int s = it * 256 + tid;
        const int q = s >> 7, r = s & 127;
        const int h = r >> 4, l = (r >> 2) & 3, p = r & 3;
        const int bq = bq0 + q;
        const int Wl = Hs[l], Hl = Hs[l];
        unsigned od = *(const unsigned*)(off + (size_t)bq * 256 + h * 32 + l * 8 + p * 2);
        float ox = bflo(od), oy = bfhi(od);
        float lgt = bflo((unsigned)awl[(size_t)bq * 128 + h * 16 + l * 4 + p]);
        float mx = lgt;
        mx = fmaxf(mx, __shfl_xor(mx, 1, 16));
        mx = fmaxf(mx, __shfl_xor(mx, 2, 16));
        mx = fmaxf(mx, __shfl_xor(mx, 4, 16));
        mx = fmaxf(mx, __shfl_xor(mx, 8, 16));
        float e = __expf(lgt - mx);
        float sum = e;
        sum += __shfl_xor(sum, 1, 16);
        sum += __shfl_xor(sum, 2, 16);
        sum += __shfl_xor(sum, 4, 16);
        sum += __shfl_xor(sum, 8, 16);
        float aw = e / sum;

        float rx = s_ref[q * 8 + l * 2 + 0];
        float ry = s_ref[q * 8 + l * 2 + 1];
        float x = rx * (float)Wl + ox - 0.5f;
        float y = ry * (float)Hl + oy - 0.5f;
        float x0f = floorf(x), y0f = floorf(y);
        float wx = x - x0f, wy = y - y0f;
        int x0 = (int)x0f, y0 = (int)y0f;
        bool vx0 = (x0 >= 0) & (x0 < Wl);
        bool vx1 = (x0 + 1 >= 0) & (x0 + 1 < Wl);
        bool vy0 = (y0 >= 0) & (y0 < Hl);
        bool vy1 = (y0 + 1 >= 0) & (y0 + 1 < Hl);
        int cx0 = min(max(x0, 0), Wl - 1);
        int cx1 = min(max(x0 + 1, 0), Wl - 1);
        int cy0 = min(max(y0, 0), Hl - 1);
        int cy1 = min(max(y0 + 1, 0), Hl - 1);
        float w00 = (vx0 && vy0) ? (1.f - wx) * (1.f - wy) * aw : 0.f;
        float w01 = (vx1 && vy0) ? wx * (1.f - wy) * aw : 0.f;
        float w10 = (vx0 && vy1) ? (1.f - wx) * wy * aw : 0.f;
        float w11 = (vx1 && vy1) ? wx * wy * aw : 0.f;
        const int rec = (q * 8 + h) * 17 + (l * 4 + p);
        s_wv[rec] = make_float4(w00, w01, w10, w11);
        s_iv[rec] = make_int4((base[l] + cy0 * Wl + cx0) << 6,
                              (base[l] + cy0 * Wl + cx1) << 6,
                              (base[l] + cy1 * Wl + cx0) << 6,
                              (base[l] + cy1 * Wl + cx1) << 6);
    }
    __syncthreads();

    const int q    = tid >> 6;
    const int lane = tid & 63;
    const int h    = lane >> 3;
    const int d4   = (lane & 7) * 4;
    const int bq   = bq0 + q;
    const int b    = bq / LQ;
    const char* vb = (const char*)vperm + (((size_t)(b * NH + h)) * LVTOT * HD + d4) * 2;

    float4 acc = make_float4(0.f, 0.f, 0.f, 0.f);
    #pragma unroll
    for (int pt = 0; pt < 16; pt++) {
        const int rec = (q * 8 + h) * 17 + pt;
        float4 w  = s_wv[rec];
        int4   iv = s_iv[rec];
        uint2 v0 = *(const uint2*)(vb + iv.x);
        uint2 v1 = *(const uint2*)(vb + iv.y);
        uint2 v2 = *(const uint2*)(vb + iv.z);
        uint2 v3 = *(const uint2*)(vb + iv.w);
        acc.x += w.x * bflo(v0.x) + w.y * bflo(v1.x) + w.z * bflo(v2.x) + w.w * bflo(v3.x);
        acc.y += w.x * bfhi(v0.x) + w.y * bfhi(v1.x) + w.z * bfhi(v2.x) + w.w * bfhi(v3.x);
        acc.z += w.x * bflo(v0.y) + w.y * bflo(v1.y) + w.z * bflo(v2.y) + w.w * bflo(v3.y);
        acc.w += w.x * bfhi(v0.y) + w.y * bfhi(v1.y) + w.z * bfhi(v2.y) + w.w * bfhi(v3.y);
    }
    ushort4 o;
    o.x = f2bf(acc.x); o.y = f2bf(acc.y); o.z = f2bf(acc.z); o.w = f2bf(acc.w);
    *(ushort4*)(sampled + (size_t)bq * 256 + h * 32 + d4) = o;
}

extern "C" void kernel_launch(void* const* d_in, const int* in_sizes, int n_in,
                              void* d_out, int out_size, void* d_ws, size_t ws_size,
                              hipStream_t stream) {
    const float* query = (const float*)d_in[0];
    const float* refp  = (const float*)d_in[1];
    const float* value = (const float*)d_in[2];
    const float* Wv    = (const float*)d_in[4];
    const float* bv    = (const float*)d_in[5];
    const float* Woff  = (const float*)d_in[6];
    const float* boff  = (const float*)d_in[7];
    const float* Wattn = (const float*)d_in[8];
    const float* battn = (const float*)d_in[9];
    const float* Wo    = (const float*)d_in[10];
    const float* bo    = (const float*)d_in[11];
    float* out = (float*)d_out;

    ushort_t* ws = (ushort_t*)d_ws;
    ushort_t* off_b   = ws;                       // 33600*256
    ushort_t* awl_b   = off_b + 8601600;          // 33600*128
    ushort_t* value_b = awl_b + 4300800;          // 34000*256
    ushort_t* query_b = value_b + 8704000;        // 33600*256 (aliased w/ sampled)
    ushort_t* vperm_b = query_b + 8601600;        // 34000*256
    ushort_t* BT      = vperm_b + 8704000;        // 896*256
    ushort_t* sampled_b = query_b;                // alias: query dead after gemm_fused

    const int M2 = BB * LQ;     // 33600

    cast_bf16<<<dim3(8500), 256, 0, stream>>>(value, value_b, 8704000 / 4);
    cast_bf16<<<dim3(8400), 256, 0, stream>>>(query, query_b, 8601600 / 4);
    prep_weights<<<dim3(896), 256, 0, stream>>>(Wv, Woff, Wattn, Wo, BT);

    gemm_fused<<<dim3(532 + 789), 256, 0, stream>>>(
        value_b, query_b, BT, bv, boff, battn, vperm_b, off_b, awl_b);

    msda_sample<<<dim3(M2 / 4), 256, 0, stream>>>(vperm_b, off_b, awl_b, refp, sampled_b);

    gemm_out<<<dim3(526), 256, 0, stream>>>(
        sampled_b, BT + 65536 + 98304, bo, out);
}